// Round 10
// baseline (854.769 us; speedup 1.0000x reference)
//
#include <hip/hip_runtime.h>
#include <math.h>

#define BB 8
#define NN 4096
#define MM 256
#define NT 256
#define CPT 16   /* contiguous columns per thread: thread t owns [16t, 16t+16) */
#define RPB 16   /* rows per block in cost_kernel */

// 5*L1 - 2*IoU, float32, same op structure/order as the jax reference
__device__ __forceinline__ float cost_fn(const float4 p, const float4 t) {
  float l1 = fabsf(p.x - t.x) + fabsf(p.y - t.y) + fabsf(p.z - t.z) + fabsf(p.w - t.w);
  float ltx = fmaxf(p.x, t.x), lty = fmaxf(p.y, t.y);
  float rbx = fminf(p.z, t.z), rby = fminf(p.w, t.w);
  float wx = rbx - ltx; wx = wx > 0.f ? wx : 0.f;
  float wy = rby - lty; wy = wy > 0.f ? wy : 0.f;
  float inter = wx * wy;
  float ap = (p.z - p.x) * (p.w - p.y);
  float at = (t.z - t.x) * (t.w - t.y);
  float un = ap + at - inter;
  float iou = inter / (un + 1e-6f);
  return 5.0f * l1 - 2.0f * iou;
}

// cost[b][n][m]: 16 rows per block, thread = m, 16 coalesced 1KB stores
__global__ void cost_kernel(const float4* __restrict__ pred,
                            const float4* __restrict__ tgt,
                            float* __restrict__ outc) {
  int blk = blockIdx.x;           // b * 256 + tile
  int b = blk >> 8;
  int n0 = (blk & 255) * RPB;
  int t = threadIdx.x;            // m
  float4 tb = tgt[b * MM + t];
  const float4* pb = pred + (size_t)b * NN + n0;
  float* out = outc + ((size_t)b * NN + n0) * MM + t;
#pragma unroll
  for (int r = 0; r < RPB; ++r)
    out[r * MM] = cost_fn(pb[r], tb);   // pb[r] is block-uniform (broadcast)
}

// costT[b][m][n] -> workspace (transposed layout for coalesced row scans)
__global__ void costT_kernel(const float4* __restrict__ pred,
                             const float4* __restrict__ tgt,
                             float* __restrict__ costT) {
  int bm = blockIdx.x;            // b*MM + m
  int b = bm >> 8;
  float4 tb = tgt[bm];
  const float4* pb = pred + (size_t)b * NN;
  float* out = costT + (size_t)bm * NN;
  int t = threadIdx.x;
#pragma unroll
  for (int k = 0; k < CPT; ++k) {
    int n = t + k * NT;
    out[n] = cost_fn(pb[n], tb);
  }
}

// lexicographic (val, pay) min; pay has col in high bits => numpy first-min
__device__ __forceinline__ void pick(double& v, unsigned& p, double v2, unsigned p2) {
  if (v2 < v || (v2 == v && p2 < p)) { v = v2; p = p2; }
}

struct LsaShared {
  double u[MM];
  double redv[2][4];
  unsigned redp[2][4];
  short row4col[NN];              // col -> assigned row, -1 free
  unsigned pathw[4 * MM];         // packed path bytes, transposed [q][t]
  int col4row[MM];
  float tx1[MM], ty1[MM], tx2[MM], ty2[MM];
};

template <bool USE_T>
__global__ void __launch_bounds__(NT, 1)
lsa_kernel(const float4* __restrict__ pred, const float4* __restrict__ tgt,
           const float* __restrict__ costT,
           float* __restrict__ out_pred, float* __restrict__ out_tgt) {
  __shared__ LsaShared S;
  const int b = blockIdx.x;
  const int t = threadIdx.x;
  const int base = t * CPT;
  const int wid = t >> 6;
  const int lane = t & 63;

  float4 pbox[CPT];               // fallback path only
  if (!USE_T) {
    const float4* pb = pred + (size_t)b * NN;
#pragma unroll
    for (int k = 0; k < CPT; ++k) pbox[k] = pb[base + k];
  }
  {
    float4 tb = tgt[b * MM + t];
    S.tx1[t] = tb.x; S.ty1[t] = tb.y; S.tx2[t] = tb.z; S.ty2[t] = tb.w;
    S.u[t] = 0.0;
    S.col4row[t] = -1;
  }
  int* r4c_i = reinterpret_cast<int*>(S.row4col);
#pragma unroll
  for (int q = 0; q < 8; ++q) r4c_i[t * 8 + q] = (int)0xFFFFFFFF;

  double v_reg[CPT];
  unsigned pay[CPT];              // (col<<9) | (row4col[col]+1)
  unsigned path_reg[CPT];
#pragma unroll
  for (int k = 0; k < CPT; ++k) {
    v_reg[k] = 0.0;
    pay[k] = ((unsigned)(base + k) << 9);
    path_reg[k] = 0;
  }
  // per-wave register mirror of u: lane l holds u[l], u[64+l], u[128+l], u[192+l]
  double um0 = 0.0, um1 = 0.0, um2 = 0.0, um3 = 0.0;
  __syncthreads();

  const float* crowT = USE_T ? (costT + (size_t)b * MM * NN) : nullptr;

  // single persistent prefetch buffer (costT immutable => never stale):
  // epilogue refills it with row cur+1, mid-Dijkstra with the runner-up row
  int pre_row = -1;
  float4 cp0, cp1, cp2, cp3;
  if (USE_T) {
    const float4* pp = reinterpret_cast<const float4*>(crowT + base);
    cp0 = pp[0]; cp1 = pp[1]; cp2 = pp[2]; cp3 = pp[3];
    pre_row = 0;                  // row 0 = first augmentation's start
  }

  for (int cur = 0; cur < MM; ++cur) {
    double spc[CPT];
#pragma unroll
    for (int k = 0; k < CPT; ++k) spc[k] = (double)INFINITY;
    unsigned scm = 0;             // SC bitmask for owned columns
    int i = cur;                  // wave-uniform scalar throughout
    double minval = 0.0;
    int parity = 0;
    int sink = -1;
    int prow = -1;                // predicted next row (from runner-up), scalar

    for (;;) {
      // ---- u[i] from register mirror: 3 cndmask + 1 shfl, no LDS on chain ----
      double ua = (i & 64) ? um1 : um0;
      double ub = (i & 64) ? um3 : um2;
      double usel = (i & 128) ? ub : ua;
      double u_i = __shfl(usel, i & 63, 64);
      // ---- acquire cost row i (scalar-uniform branch: hit path issues nothing) ----
      float c[CPT];
      if (USE_T) {
        float4 q0, q1, q2, q3;
        if (i == pre_row) {
          q0 = cp0; q1 = cp1; q2 = cp2; q3 = cp3;
        } else {
          const float4* rp = reinterpret_cast<const float4*>(crowT + (size_t)i * NN + base);
          q0 = rp[0]; q1 = rp[1]; q2 = rp[2]; q3 = rp[3];
        }
        // prefetch predicted next row (overlaps scan+butterfly+barrier)
        if (prow >= 0 && prow != i && prow != pre_row) {
          const float4* pp = reinterpret_cast<const float4*>(crowT + (size_t)prow * NN + base);
          cp0 = pp[0]; cp1 = pp[1]; cp2 = pp[2]; cp3 = pp[3];
          pre_row = prow;
        }
        c[0] = q0.x; c[1] = q0.y; c[2] = q0.z; c[3] = q0.w;
        c[4] = q1.x; c[5] = q1.y; c[6] = q1.z; c[7] = q1.w;
        c[8] = q2.x; c[9] = q2.y; c[10] = q2.z; c[11] = q2.w;
        c[12] = q3.x; c[13] = q3.y; c[14] = q3.z; c[15] = q3.w;
      } else {
        float4 tb = make_float4(S.tx1[i], S.ty1[i], S.tx2[i], S.ty2[i]);
#pragma unroll
        for (int k = 0; k < CPT; ++k) c[k] = cost_fn(pbox[k], tb);
      }
      // ---- scan: update spc/path, running local argmin (k asc => first-min) ----
      double bestv = (double)INFINITY;
      unsigned bestp = 0xFFFFFFFFu;
#pragma unroll
      for (int k = 0; k < CPT; ++k) {
        bool open = !((scm >> k) & 1u);
        // numpy op order: ((min_val + cost) - u[i]) - v[j], all f64
        double r = ((minval + (double)c[k]) - u_i) - v_reg[k];
        if (open && r < spc[k]) { spc[k] = r; path_reg[k] = (unsigned)i; }
        if (open && spc[k] < bestv) { bestv = spc[k]; bestp = pay[k]; }
      }
      // ---- wave butterfly (lexicographic (val, pay)) ----
#pragma unroll
      for (int off = 1; off <= 32; off <<= 1) {
        double ov = __shfl_xor(bestv, off);
        unsigned op = __shfl_xor(bestp, off);
        pick(bestv, bestp, ov, op);
      }
      if ((t & 63) == 0) { S.redv[parity][wid] = bestv; S.redp[parity][wid] = bestp; }
      __syncthreads();            // the only barrier per step
      // ---- tournament merge: exact winner + runner-up predictor ----
      double a0 = S.redv[parity][0], a1 = S.redv[parity][1];
      double a2 = S.redv[parity][2], a3 = S.redv[parity][3];
      unsigned b0 = S.redp[parity][0], b1 = S.redp[parity][1];
      unsigned b2 = S.redp[parity][2], b3 = S.redp[parity][3];
      parity ^= 1;
      double lo0 = a0, hi0 = a1; unsigned lp0 = b0, hp0 = b1;
      if (a1 < a0 || (a1 == a0 && b1 < b0)) { lo0 = a1; lp0 = b1; hi0 = a0; hp0 = b0; }
      double lo1 = a2, hi1 = a3; unsigned lp1 = b2, hp1 = b3;
      if (a3 < a2 || (a3 == a2 && b3 < b2)) { lo1 = a3; lp1 = b3; hi1 = a2; hp1 = b2; }
      double wv, rv; unsigned wp, rp;
      if (lo1 < lo0 || (lo1 == lo0 && lp1 < lp0)) {
        wv = lo1; wp = lp1; rv = lo0; rp = lp0; pick(rv, rp, hi1, hp1);
      } else {
        wv = lo0; wp = lp0; rv = lo1; rp = lp1; pick(rv, rp, hi0, hp0);
      }
      minval = wv;
      int mj = (int)(wp >> 9);
      int rc = (int)(wp & 511u) - 1;        // row4col[mj], carried through the reduce
      if ((mj >> 4) == t) scm |= (1u << (mj & 15));
      if (rc < 0) { sink = mj; break; }
      i = __builtin_amdgcn_readfirstlane(rc);            // scalar: uniform branches
      prow = __builtin_amdgcn_readfirstlane((int)(rp & 511u) - 1);
    }

    // ---- prefetch next augmentation's start row (overlaps epilogue) ----
    if (USE_T && cur + 1 < MM) {
      const float4* pp = reinterpret_cast<const float4*>(crowT + (size_t)(cur + 1) * NN + base);
      cp0 = pp[0]; cp1 = pp[1]; cp2 = pp[2]; cp3 = pp[3];
      pre_row = cur + 1;
    }

    // ---- dual updates (SR\{cur} == {row4col[j] : j in SC, matched} bijection) ----
#pragma unroll
    for (int k = 0; k < CPT; ++k) {
      if ((scm >> k) & 1u) {
        double d = minval - spc[k];
        int rc2 = (int)(pay[k] & 511u) - 1;   // pre-augment row4col
        if (rc2 >= 0) S.u[rc2] += d;          // distinct rc2 => race-free; never cur
        v_reg[k] -= d;
      }
    }
    if (t == cur) S.u[t] += minval;
    // ---- publish path registers (transposed words: conflict-free) ----
#pragma unroll
    for (int q = 0; q < 4; ++q) {
      unsigned w = (path_reg[4 * q] & 255u) | ((path_reg[4 * q + 1] & 255u) << 8) |
                   ((path_reg[4 * q + 2] & 255u) << 16) | ((path_reg[4 * q + 3] & 255u) << 24);
      S.pathw[q * MM + t] = w;
    }
    __syncthreads();
    // ---- augment along alternating path (short serial walk) ----
    if (t == 0) {
      int j = sink;
      for (;;) {
        unsigned w = S.pathw[((j >> 2) & 3) * MM + (j >> 4)];
        int i2 = (int)((w >> ((j & 3) * 8)) & 255u);
        S.row4col[j] = (short)i2;
        int tmp = S.col4row[i2];
        S.col4row[i2] = j;
        j = tmp;
        if (i2 == cur) break;
      }
    }
    __syncthreads();
    // ---- refresh pay + u mirror (once per augmentation, off-path) ----
    um0 = S.u[lane]; um1 = S.u[lane + 64]; um2 = S.u[lane + 128]; um3 = S.u[lane + 192];
#pragma unroll
    for (int q = 0; q < 8; ++q) {
      int w = r4c_i[t * 8 + q];
      int r0 = (int)(short)(w & 0xFFFF);
      int r1 = (w >> 16);                  // arithmetic shift sign-extends
      pay[2 * q] = ((unsigned)(base + 2 * q) << 9) | (unsigned)(r0 + 1);
      pay[2 * q + 1] = ((unsigned)(base + 2 * q + 1) << 9) | (unsigned)(r1 + 1);
    }
  }

  // ---- outputs: argsort of the assignment permutation ----
  {
    int myc = S.col4row[t];
    int rank = 0;
    for (int r = 0; r < MM; ++r) rank += (S.col4row[r] < myc) ? 1 : 0;
    out_pred[(size_t)b * MM + rank] = (float)myc;
    out_tgt[(size_t)b * MM + rank] = (float)t;
  }
}

extern "C" void kernel_launch(void* const* d_in, const int* in_sizes, int n_in,
                              void* d_out, int out_size, void* d_ws, size_t ws_size,
                              hipStream_t stream) {
  const float4* pred = (const float4*)d_in[0];   // [B,N,4] f32
  const float4* tgt  = (const float4*)d_in[1];   // [B,M,4] f32

  float* outc = (float*)d_out;
  float* out_pred = outc + (size_t)BB * NN * MM;
  float* out_tgt = out_pred + (size_t)BB * MM;
  float* costT = (float*)d_ws;
  const size_t needT = (size_t)BB * MM * NN * sizeof(float);  // 33.5 MB

  cost_kernel<<<dim3(BB * NN / RPB), dim3(MM), 0, stream>>>(pred, tgt, outc);

  if (ws_size >= needT) {
    costT_kernel<<<dim3(BB * MM), dim3(NT), 0, stream>>>(pred, tgt, costT);
    lsa_kernel<true><<<dim3(BB), dim3(NT), 0, stream>>>(pred, tgt, costT, out_pred, out_tgt);
  } else {
    lsa_kernel<false><<<dim3(BB), dim3(NT), 0, stream>>>(pred, tgt, nullptr, out_pred, out_tgt);
  }
}

// Round 11
// 174.505 us; speedup vs baseline: 4.8983x; 4.8983x over previous
//
#include <hip/hip_runtime.h>
#include <math.h>

#define BB 8
#define NN 4096
#define MM 256
#define NT 256
#define CPT 16   /* contiguous columns per thread: thread t owns [16t, 16t+16) */
#define RPB 16   /* rows per block in cost_kernel */

// 5*L1 - 2*IoU, float32, same op structure/order as the jax reference
__device__ __forceinline__ float cost_fn(const float4 p, const float4 t) {
  float l1 = fabsf(p.x - t.x) + fabsf(p.y - t.y) + fabsf(p.z - t.z) + fabsf(p.w - t.w);
  float ltx = fmaxf(p.x, t.x), lty = fmaxf(p.y, t.y);
  float rbx = fminf(p.z, t.z), rby = fminf(p.w, t.w);
  float wx = rbx - ltx; wx = wx > 0.f ? wx : 0.f;
  float wy = rby - lty; wy = wy > 0.f ? wy : 0.f;
  float inter = wx * wy;
  float ap = (p.z - p.x) * (p.w - p.y);
  float at = (t.z - t.x) * (t.w - t.y);
  float un = ap + at - inter;
  float iou = inter / (un + 1e-6f);
  return 5.0f * l1 - 2.0f * iou;
}

// cost[b][n][m]: 16 rows per block, thread = m, 16 coalesced 1KB stores
__global__ void cost_kernel(const float4* __restrict__ pred,
                            const float4* __restrict__ tgt,
                            float* __restrict__ outc) {
  int blk = blockIdx.x;           // b * 256 + tile
  int b = blk >> 8;
  int n0 = (blk & 255) * RPB;
  int t = threadIdx.x;            // m
  float4 tb = tgt[b * MM + t];
  const float4* pb = pred + (size_t)b * NN + n0;
  float* out = outc + ((size_t)b * NN + n0) * MM + t;
#pragma unroll
  for (int r = 0; r < RPB; ++r)
    out[r * MM] = cost_fn(pb[r], tb);   // pb[r] is block-uniform (broadcast)
}

// costT[b][m][n] + fused row-min/argmin (JV column-reduction duals)
__global__ void costT_kernel(const float4* __restrict__ pred,
                             const float4* __restrict__ tgt,
                             float* __restrict__ costT,
                             float* __restrict__ u0,
                             int* __restrict__ amin) {
  __shared__ float s_v[4];
  __shared__ int s_c[4];
  int bm = blockIdx.x;            // b*MM + m
  int b = bm >> 8;
  float4 tb = tgt[bm];
  const float4* pb = pred + (size_t)b * NN;
  float* out = costT + (size_t)bm * NN;
  int t = threadIdx.x;
  float bv = INFINITY; int bc = 0x7fffffff;
#pragma unroll
  for (int k = 0; k < CPT; ++k) {
    int n = t + k * NT;           // coalesced
    float cv = cost_fn(pb[n], tb);
    out[n] = cv;
    if (cv < bv || (cv == bv && n < bc)) { bv = cv; bc = n; }  // n asc per thread
  }
#pragma unroll
  for (int off = 1; off <= 32; off <<= 1) {
    float ov = __shfl_xor(bv, off);
    int oc = __shfl_xor(bc, off);
    if (ov < bv || (ov == bv && oc < bc)) { bv = ov; bc = oc; }
  }
  if ((t & 63) == 0) { s_v[t >> 6] = bv; s_c[t >> 6] = bc; }
  __syncthreads();
  if (t == 0) {
    float mv = s_v[0]; int mc = s_c[0];
    for (int w = 1; w < 4; ++w)
      if (s_v[w] < mv || (s_v[w] == mv && s_c[w] < mc)) { mv = s_v[w]; mc = s_c[w]; }
    u0[bm] = mv;                  // u[i] = row min (exact f32, feasible dual)
    amin[bm] = mc;
  }
}

// lexicographic (val, pay) min; pay has col in high bits => numpy first-min
__device__ __forceinline__ void pick(double& v, unsigned& p, double v2, unsigned p2) {
  if (v2 < v || (v2 == v && p2 < p)) { v = v2; p = p2; }
}

struct LsaShared {
  double u[MM];
  double redv[2][4];
  unsigned redp[2][4];
  short row4col[NN];              // col -> assigned row, -1 free
  unsigned pathw[4 * MM];         // packed path bytes, transposed [q][t]
  int col4row[MM];
  int aminS[MM];
  short freelist[MM];
  int s_nf;
  float tx1[MM], ty1[MM], tx2[MM], ty2[MM];
};

template <bool USE_T>
__global__ void __launch_bounds__(NT, 1)
lsa_kernel(const float4* __restrict__ pred, const float4* __restrict__ tgt,
           const float* __restrict__ costT,
           const float* __restrict__ u0, const int* __restrict__ amin,
           float* __restrict__ out_pred, float* __restrict__ out_tgt) {
  __shared__ LsaShared S;
  const int b = blockIdx.x;
  const int t = threadIdx.x;
  const int base = t * CPT;
  const int wid = t >> 6;

  float4 pbox[CPT];               // fallback path only
  if (!USE_T) {
    const float4* pb = pred + (size_t)b * NN;
#pragma unroll
    for (int k = 0; k < CPT; ++k) pbox[k] = pb[base + k];
  }
  {
    float4 tb = tgt[b * MM + t];
    S.tx1[t] = tb.x; S.ty1[t] = tb.y; S.tx2[t] = tb.z; S.ty2[t] = tb.w;
    S.u[t] = USE_T ? (double)u0[b * MM + t] : 0.0;   // exact f32 -> f64
    S.col4row[t] = -1;
    S.aminS[t] = USE_T ? amin[b * MM + t] : 0;
  }
  int* r4c_i = reinterpret_cast<int*>(S.row4col);
#pragma unroll
  for (int q = 0; q < 8; ++q) r4c_i[t * 8 + q] = (int)0xFFFFFFFF;

  double v_reg[CPT];
  unsigned pay[CPT];              // (col<<9) | (row4col[col]+1)
  unsigned path_reg[CPT];
#pragma unroll
  for (int k = 0; k < CPT; ++k) {
    v_reg[k] = 0.0;
    path_reg[k] = 0;
  }
  __syncthreads();

  // ---- greedy init: row i takes its argmin col if free (row order, serial) ----
  if (t == 0) {
    int nf = 0;
    if (USE_T) {
      for (int i2 = 0; i2 < MM; ++i2) {
        int j = S.aminS[i2];
        if (S.row4col[j] < 0) { S.row4col[j] = (short)i2; S.col4row[i2] = j; }
        else S.freelist[nf++] = (short)i2;
      }
    } else {
      for (int i2 = 0; i2 < MM; ++i2) S.freelist[nf++] = (short)i2;
    }
    S.s_nf = nf;
  }
  __syncthreads();
  const int nf = S.s_nf;

  // ---- initial pay snapshot (post-greedy row4col) ----
#pragma unroll
  for (int q = 0; q < 8; ++q) {
    int w = r4c_i[t * 8 + q];
    int r0 = (int)(short)(w & 0xFFFF);
    int r1 = (w >> 16);
    pay[2 * q] = ((unsigned)(base + 2 * q) << 9) | (unsigned)(r0 + 1);
    pay[2 * q + 1] = ((unsigned)(base + 2 * q + 1) << 9) | (unsigned)(r1 + 1);
  }

  const float* crowT = USE_T ? (costT + (size_t)b * MM * NN) : nullptr;

  // single persistent prefetch buffer (costT immutable => never stale)
  int pre_row = -1;
  float4 cp0, cp1, cp2, cp3;
  if (USE_T && nf > 0) {
    int r0 = (int)S.freelist[0];
    const float4* pp = reinterpret_cast<const float4*>(crowT + (size_t)r0 * NN + base);
    cp0 = pp[0]; cp1 = pp[1]; cp2 = pp[2]; cp3 = pp[3];
    pre_row = r0;
  }

  for (int fi = 0; fi < nf; ++fi) {
    const int cur = (int)S.freelist[fi];
    double spc[CPT];
#pragma unroll
    for (int k = 0; k < CPT; ++k) spc[k] = (double)INFINITY;
    unsigned scm = 0;             // SC bitmask for owned columns
    int i = cur;
    double minval = 0.0;
    int parity = 0;
    int sink = -1;
    int prow = -1;                // predicted next row (from runner-up)

    for (;;) {
      // ---- acquire cost row i (single-compare select) ----
      float c[CPT];
      if (USE_T) {
        float4 q0, q1, q2, q3;
        if (i == pre_row) {
          q0 = cp0; q1 = cp1; q2 = cp2; q3 = cp3;
        } else {
          const float4* rp = reinterpret_cast<const float4*>(crowT + (size_t)i * NN + base);
          q0 = rp[0]; q1 = rp[1]; q2 = rp[2]; q3 = rp[3];
        }
        // prefetch predicted next row (overlaps scan+butterfly+barrier)
        if (prow >= 0 && prow != i && prow != pre_row) {
          const float4* pp = reinterpret_cast<const float4*>(crowT + (size_t)prow * NN + base);
          cp0 = pp[0]; cp1 = pp[1]; cp2 = pp[2]; cp3 = pp[3];
          pre_row = prow;
        }
        c[0] = q0.x; c[1] = q0.y; c[2] = q0.z; c[3] = q0.w;
        c[4] = q1.x; c[5] = q1.y; c[6] = q1.z; c[7] = q1.w;
        c[8] = q2.x; c[9] = q2.y; c[10] = q2.z; c[11] = q2.w;
        c[12] = q3.x; c[13] = q3.y; c[14] = q3.z; c[15] = q3.w;
      } else {
        float4 tb = make_float4(S.tx1[i], S.ty1[i], S.tx2[i], S.ty2[i]);
#pragma unroll
        for (int k = 0; k < CPT; ++k) c[k] = cost_fn(pbox[k], tb);
      }
      double u_i = S.u[i];
      // ---- scan: update spc/path, running local argmin (k asc => first-min) ----
      double bestv = (double)INFINITY;
      unsigned bestp = 0xFFFFFFFFu;
#pragma unroll
      for (int k = 0; k < CPT; ++k) {
        bool open = !((scm >> k) & 1u);
        // shortest-path cost: ((min_val + cost) - u[i]) - v[j], all f64
        double r = ((minval + (double)c[k]) - u_i) - v_reg[k];
        if (open && r < spc[k]) { spc[k] = r; path_reg[k] = (unsigned)i; }
        if (open && spc[k] < bestv) { bestv = spc[k]; bestp = pay[k]; }
      }
      // ---- wave butterfly (lexicographic (val, pay)) ----
#pragma unroll
      for (int off = 1; off <= 32; off <<= 1) {
        double ov = __shfl_xor(bestv, off);
        unsigned op = __shfl_xor(bestp, off);
        pick(bestv, bestp, ov, op);
      }
      if ((t & 63) == 0) { S.redv[parity][wid] = bestv; S.redp[parity][wid] = bestp; }
      __syncthreads();            // the only barrier per step
      // ---- tournament merge: exact winner + runner-up predictor ----
      double a0 = S.redv[parity][0], a1 = S.redv[parity][1];
      double a2 = S.redv[parity][2], a3 = S.redv[parity][3];
      unsigned b0 = S.redp[parity][0], b1 = S.redp[parity][1];
      unsigned b2 = S.redp[parity][2], b3 = S.redp[parity][3];
      parity ^= 1;
      double lo0 = a0, hi0 = a1; unsigned lp0 = b0, hp0 = b1;
      if (a1 < a0 || (a1 == a0 && b1 < b0)) { lo0 = a1; lp0 = b1; hi0 = a0; hp0 = b0; }
      double lo1 = a2, hi1 = a3; unsigned lp1 = b2, hp1 = b3;
      if (a3 < a2 || (a3 == a2 && b3 < b2)) { lo1 = a3; lp1 = b3; hi1 = a2; hp1 = b2; }
      double wv, rv; unsigned wp, rp;
      if (lo1 < lo0 || (lo1 == lo0 && lp1 < lp0)) {
        wv = lo1; wp = lp1; rv = lo0; rp = lp0; pick(rv, rp, hi1, hp1);
      } else {
        wv = lo0; wp = lp0; rv = lo1; rp = lp1; pick(rv, rp, hi0, hp0);
      }
      minval = wv;
      int mj = (int)(wp >> 9);
      int rc = (int)(wp & 511u) - 1;        // row4col[mj], carried through the reduce
      prow = (int)(rp & 511u) - 1;          // runner-up's row = predicted next
      if ((mj >> 4) == t) scm |= (1u << (mj & 15));
      if (rc < 0) { sink = mj; break; }
      i = rc;
    }

    // ---- prefetch next free row's cost row (overlaps epilogue) ----
    if (USE_T && fi + 1 < nf) {
      int nr = (int)S.freelist[fi + 1];
      const float4* pp = reinterpret_cast<const float4*>(crowT + (size_t)nr * NN + base);
      cp0 = pp[0]; cp1 = pp[1]; cp2 = pp[2]; cp3 = pp[3];
      pre_row = nr;
    }

    // ---- dual updates (SR\{cur} == {row4col[j] : j in SC, matched} bijection) ----
#pragma unroll
    for (int k = 0; k < CPT; ++k) {
      if ((scm >> k) & 1u) {
        double d = minval - spc[k];
        int rc2 = (int)(pay[k] & 511u) - 1;   // pre-augment row4col
        if (rc2 >= 0) S.u[rc2] += d;          // distinct rc2 => race-free; never cur
        v_reg[k] -= d;
      }
    }
    if (t == cur) S.u[t] += minval;
    // ---- publish path registers (transposed words: conflict-free) ----
#pragma unroll
    for (int q = 0; q < 4; ++q) {
      unsigned w = (path_reg[4 * q] & 255u) | ((path_reg[4 * q + 1] & 255u) << 8) |
                   ((path_reg[4 * q + 2] & 255u) << 16) | ((path_reg[4 * q + 3] & 255u) << 24);
      S.pathw[q * MM + t] = w;
    }
    __syncthreads();
    // ---- augment along alternating path (short serial walk) ----
    if (t == 0) {
      int j = sink;
      for (;;) {
        unsigned w = S.pathw[((j >> 2) & 3) * MM + (j >> 4)];
        int i2 = (int)((w >> ((j & 3) * 8)) & 255u);
        S.row4col[j] = (short)i2;
        int tmp = S.col4row[i2];
        S.col4row[i2] = j;
        j = tmp;
        if (i2 == cur) break;
      }
    }
    __syncthreads();
    // ---- refresh pay for owned cols (8 packed int reads, once per augmentation) ----
#pragma unroll
    for (int q = 0; q < 8; ++q) {
      int w = r4c_i[t * 8 + q];
      int r0 = (int)(short)(w & 0xFFFF);
      int r1 = (w >> 16);                  // arithmetic shift sign-extends
      pay[2 * q] = ((unsigned)(base + 2 * q) << 9) | (unsigned)(r0 + 1);
      pay[2 * q + 1] = ((unsigned)(base + 2 * q + 1) << 9) | (unsigned)(r1 + 1);
    }
  }

  // ---- outputs: argsort of the assignment permutation ----
  {
    int myc = S.col4row[t];
    int rank = 0;
    for (int r = 0; r < MM; ++r) rank += (S.col4row[r] < myc) ? 1 : 0;
    out_pred[(size_t)b * MM + rank] = (float)myc;
    out_tgt[(size_t)b * MM + rank] = (float)t;
  }
}

extern "C" void kernel_launch(void* const* d_in, const int* in_sizes, int n_in,
                              void* d_out, int out_size, void* d_ws, size_t ws_size,
                              hipStream_t stream) {
  const float4* pred = (const float4*)d_in[0];   // [B,N,4] f32
  const float4* tgt  = (const float4*)d_in[1];   // [B,M,4] f32

  float* outc = (float*)d_out;
  float* out_pred = outc + (size_t)BB * NN * MM;
  float* out_tgt = out_pred + (size_t)BB * MM;
  float* costT = (float*)d_ws;
  float* u0 = costT + (size_t)BB * MM * NN;
  int* amin = (int*)(u0 + (size_t)BB * MM);
  const size_t needT = (size_t)BB * MM * NN * sizeof(float) + 2u * BB * MM * sizeof(float);

  cost_kernel<<<dim3(BB * NN / RPB), dim3(MM), 0, stream>>>(pred, tgt, outc);

  if (ws_size >= needT) {
    costT_kernel<<<dim3(BB * MM), dim3(NT), 0, stream>>>(pred, tgt, costT, u0, amin);
    lsa_kernel<true><<<dim3(BB), dim3(NT), 0, stream>>>(pred, tgt, costT, u0, amin,
                                                        out_pred, out_tgt);
  } else {
    lsa_kernel<false><<<dim3(BB), dim3(NT), 0, stream>>>(pred, tgt, nullptr, nullptr, nullptr,
                                                         out_pred, out_tgt);
  }
}